// Round 16
// baseline (658.429 us; speedup 1.0000x reference)
//
#include <hip/hip_runtime.h>

#define N_USERS 50000
#define NN0 200000
#define NN1 50000
#define NN2 12500
#define EE0 1600000
#define EE1 400000
#define EE2 100000

#define ENC_BLOCKS 782     // (50000+63)/64
#define CNT_BLOCKS 2295    // (587500+255)/256

// Padded segment geometry (1024 multiples):
// seg:      0:e0        1:e1      2:e2      3:parent1  4:parent2
// deg off:  0           200704    250880    264192     314368   (total 327680)
// scan blk: 196         49        13        49         13       (cum 196,245,258,307,320)
// bsum off: 0           196       245       258        307
// el off:   0           1600000   2000000   2100000    2300000

// ================= K1: encoder (blocks<782, reg-prefetch) + CSR count ========
__global__ __launch_bounds__(256) void k_enc_count(
    const float* __restrict__ xr,
    const float* __restrict__ Wd, const float* __restrict__ bd,
    const float* __restrict__ Wt, const float* __restrict__ bt,
    const float* __restrict__ Wn, const float* __restrict__ bn,
    const float* __restrict__ Wc, const float* __restrict__ bc,
    float* __restrict__ h128,
    const int* __restrict__ d0, const int* __restrict__ d1, const int* __restrict__ d2,
    const int* __restrict__ p1, const int* __restrict__ p2,
    int* __restrict__ degs, int* __restrict__ ranks)
{
    __shared__ float XsB[4368];    // [0,2176): des [k][row]; [2192,4368): tweet
    __shared__ float Ws[32][68];
    __shared__ float xnc[64][8];
    __shared__ float Wl[8][64];

    if (blockIdx.x >= ENC_BLOCKS) {
        // ---------------- CSR count path ----------------
        int t0 = (blockIdx.x - ENC_BLOCKS) * 256 + threadIdx.x;
        if (t0 >= 587500) return;
        #pragma unroll
        for (int k = 0; k < 4; k++) {
            int gid = t0 + k * 587500;
            int idx;
            if (gid < 1600000)      idx = d0[gid];
            else if (gid < 2000000) idx = 200704 + d1[gid - 1600000];
            else if (gid < 2100000) idx = 250880 + d2[gid - 2000000];
            else if (gid < 2300000) idx = 264192 + p1[gid - 2100000];
            else                    idx = 314368 + p2[gid - 2300000];
            ranks[gid] = atomicAdd(&degs[idx], 1);
        }
        return;
    }

    // ---------------- encoder path ----------------
    int t = threadIdx.x;
    int lane = t & 63, wv = t >> 6;
    int cg = t & 15, rg = t >> 4;
    int base = blockIdx.x * 64;

    if (t < 64) {
        int row = base + t;
        if (row < N_USERS) {
            const float* xp = xr + (size_t)row * 1544;
            float4 a = *(const float4*)xp;
            float2 b2 = *(const float2*)(xp + 4);
            float2 c2 = *(const float2*)(xp + 774);
            xnc[t][0] = a.x; xnc[t][1] = a.y; xnc[t][2] = a.z; xnc[t][3] = a.w;
            xnc[t][4] = b2.x; xnc[t][5] = b2.y; xnc[t][6] = c2.x; xnc[t][7] = c2.y;
        } else {
            #pragma unroll
            for (int k = 0; k < 8; k++) xnc[t][k] = 0.f;
        }
    } else if (t >= 192) {
        int l = t - 192;
        #pragma unroll
        for (int k = 0; k < 8; k++) {
            float w = 0.f;
            if (l < 32) { if (k < 6) w = Wn[k * 32 + l]; }
            else        { if (k >= 6) w = Wc[(k - 6) * 32 + (l - 32)]; }
            Wl[k][l] = w;
        }
    }

    // staging geometry (constant per thread): conflict-free map (R11)
    int srow = (lane & 15) + wv * 16;
    int q0 = (lane >> 4);          // h=0: q0, h=1: q0+4
    int grow = base + srow;
    bool vrow = grow < N_USERS;
    const float* xrow = xr + (size_t)grow * 1544;
    int wk0 = t >> 4;              // W-stage h=0: k index
    int wc40 = (t & 15) * 4;       //             col*4
    int wk1 = (t + 256) >> 4;      // h=1
    int wc41 = wc40;               // (t+256)&15 == t&15

    // prefetch registers (named, straight-line)
    float4 vd0, vd1; float2 va0, va1, vb0, vb1; float4 w0r, w1r;

    // prologue: load chunk 0
    {
        vd0 = make_float4(0.f, 0.f, 0.f, 0.f); vd1 = vd0;
        va0 = make_float2(0.f, 0.f); va1 = va0; vb0 = va0; vb1 = va0;
        if (vrow) {
            const float* xp0 = xrow + q0 * 4;
            vd0 = *(const float4*)(xp0 + 776);
            va0 = *(const float2*)(xp0 + 6);
            vb0 = *(const float2*)(xp0 + 8);
            const float* xp1 = xrow + (q0 + 4) * 4;
            vd1 = *(const float4*)(xp1 + 776);
            va1 = *(const float2*)(xp1 + 6);
            vb1 = *(const float2*)(xp1 + 8);
        }
        w0r = (wc40 < 32) ? *(const float4*)(Wd + (size_t)wk0 * 32 + wc40)
                          : *(const float4*)(Wt + (size_t)wk0 * 32 + (wc40 - 32));
        w1r = (wc41 < 32) ? *(const float4*)(Wd + (size_t)wk1 * 32 + wc41)
                          : *(const float4*)(Wt + (size_t)wk1 * 32 + (wc41 - 32));
    }

    float acc[4][4];
    #pragma unroll
    for (int r = 0; r < 4; r++)
        #pragma unroll
        for (int c = 0; c < 4; c++) acc[r][c] = 0.f;

    for (int kc = 0; kc < 768; kc += 32) {
        __syncthreads();
        // write prefetched regs -> LDS (conflict-free map)
        {
            int k0 = q0 * 4;
            XsB[(k0 + 0) * 68 + srow] = vd0.x;
            XsB[(k0 + 1) * 68 + srow] = vd0.y;
            XsB[(k0 + 2) * 68 + srow] = vd0.z;
            XsB[(k0 + 3) * 68 + srow] = vd0.w;
            XsB[2192 + (k0 + 0) * 68 + srow] = va0.x;
            XsB[2192 + (k0 + 1) * 68 + srow] = va0.y;
            XsB[2192 + (k0 + 2) * 68 + srow] = vb0.x;
            XsB[2192 + (k0 + 3) * 68 + srow] = vb0.y;
            int k1 = (q0 + 4) * 4;
            XsB[(k1 + 0) * 68 + srow] = vd1.x;
            XsB[(k1 + 1) * 68 + srow] = vd1.y;
            XsB[(k1 + 2) * 68 + srow] = vd1.z;
            XsB[(k1 + 3) * 68 + srow] = vd1.w;
            XsB[2192 + (k1 + 0) * 68 + srow] = va1.x;
            XsB[2192 + (k1 + 1) * 68 + srow] = va1.y;
            XsB[2192 + (k1 + 2) * 68 + srow] = vb1.x;
            XsB[2192 + (k1 + 3) * 68 + srow] = vb1.y;
            *(float4*)&Ws[wk0][wc40] = w0r;
            *(float4*)&Ws[wk1][wc41] = w1r;
        }
        __syncthreads();

        // issue next-chunk loads (wrap to 0 on last iter; redundant, harmless)
        {
            int kn = (kc + 32 == 768) ? 0 : kc + 32;
            if (vrow) {
                const float* xp0 = xrow + kn + q0 * 4;
                vd0 = *(const float4*)(xp0 + 776);
                va0 = *(const float2*)(xp0 + 6);
                vb0 = *(const float2*)(xp0 + 8);
                const float* xp1 = xrow + kn + (q0 + 4) * 4;
                vd1 = *(const float4*)(xp1 + 776);
                va1 = *(const float2*)(xp1 + 6);
                vb1 = *(const float2*)(xp1 + 8);
            }
            w0r = (wc40 < 32) ? *(const float4*)(Wd + (size_t)(kn + wk0) * 32 + wc40)
                              : *(const float4*)(Wt + (size_t)(kn + wk0) * 32 + (wc40 - 32));
            w1r = (wc41 < 32) ? *(const float4*)(Wd + (size_t)(kn + wk1) * 32 + wc41)
                              : *(const float4*)(Wt + (size_t)(kn + wk1) * 32 + (wc41 - 32));
        }

        const float* Xp = (cg < 8) ? XsB : (XsB + 2192);
        #pragma unroll 8
        for (int k = 0; k < 32; k++) {
            float4 xv = *(const float4*)(Xp + k * 68 + rg * 4);
            float4 wv2 = *(const float4*)&Ws[k][cg * 4];
            acc[0][0] = fmaf(xv.x, wv2.x, acc[0][0]);
            acc[0][1] = fmaf(xv.x, wv2.y, acc[0][1]);
            acc[0][2] = fmaf(xv.x, wv2.z, acc[0][2]);
            acc[0][3] = fmaf(xv.x, wv2.w, acc[0][3]);
            acc[1][0] = fmaf(xv.y, wv2.x, acc[1][0]);
            acc[1][1] = fmaf(xv.y, wv2.y, acc[1][1]);
            acc[1][2] = fmaf(xv.y, wv2.z, acc[1][2]);
            acc[1][3] = fmaf(xv.y, wv2.w, acc[1][3]);
            acc[2][0] = fmaf(xv.z, wv2.x, acc[2][0]);
            acc[2][1] = fmaf(xv.z, wv2.y, acc[2][1]);
            acc[2][2] = fmaf(xv.z, wv2.z, acc[2][2]);
            acc[2][3] = fmaf(xv.z, wv2.w, acc[2][3]);
            acc[3][0] = fmaf(xv.w, wv2.x, acc[3][0]);
            acc[3][1] = fmaf(xv.w, wv2.y, acc[3][1]);
            acc[3][2] = fmaf(xv.w, wv2.z, acc[3][2]);
            acc[3][3] = fmaf(xv.w, wv2.w, acc[3][3]);
        }
    }

    float bh[4], bl[4], wlv[8][4];
    #pragma unroll
    for (int c = 0; c < 4; c++) {
        int j = cg * 4 + c;
        bh[c] = (j < 32) ? bd[j] : bt[j - 32];
        bl[c] = (j < 32) ? bn[j] : bc[j - 32];
        #pragma unroll
        for (int k = 0; k < 8; k++) wlv[k][c] = Wl[k][j];
    }
    #pragma unroll
    for (int r = 0; r < 4; r++) {
        int lr = rg * 4 + r;
        int row = base + lr;
        if (row >= N_USERS) break;
        float4 hv;
        float* ph = &hv.x;
        #pragma unroll
        for (int c = 0; c < 4; c++) {
            float v = acc[r][c] + bh[c];
            ph[c] = v > 0.f ? v : 0.01f * v;
        }
        *(float4*)(h128 + (size_t)row * 128 + cg * 4) = hv;
        float4 lv;
        float* pl = &lv.x;
        #pragma unroll
        for (int c = 0; c < 4; c++) {
            float v = bl[c];
            #pragma unroll
            for (int k = 0; k < 8; k++) v = fmaf(xnc[lr][k], wlv[k][c], v);
            pl[c] = v > 0.f ? v : 0.01f * v;
        }
        *(float4*)(h128 + (size_t)row * 128 + 64 + cg * 4) = lv;
    }
}

// ---------------- dedicated atomic-free scatter (no LDS, high occupancy) -----
__global__ __launch_bounds__(256) void k_scatter_all(
    const int* __restrict__ s0, const int* __restrict__ d0,
    const int* __restrict__ s1, const int* __restrict__ d1,
    const int* __restrict__ s2, const int* __restrict__ d2,
    const int* __restrict__ p1, const int* __restrict__ p2,
    const int* __restrict__ nl, const float* __restrict__ dinvs,
    const int* __restrict__ rowsts, const int* __restrict__ ranks,
    int* __restrict__ elists, float* __restrict__ edw)
{
    int t0 = blockIdx.x * 256 + threadIdx.x;
    if (t0 >= 587500) return;
    #pragma unroll
    for (int k = 0; k < 4; k++) {
        int gid = t0 + k * 587500;
        if (gid < 1600000) {
            int s = s0[gid];
            int p = rowsts[d0[gid]] + ranks[gid];
            elists[p] = nl[s];
            edw[p] = dinvs[s];
        } else if (gid < 2000000) {
            int i = gid - 1600000;
            int s = s1[i];
            int p = rowsts[200704 + d1[i]] + ranks[gid];
            elists[1600000 + p] = s;
            edw[1600000 + p] = dinvs[200704 + s];
        } else if (gid < 2100000) {
            int i = gid - 2000000;
            int s = s2[i];
            int p = rowsts[250880 + d2[i]] + ranks[gid];
            elists[2000000 + p] = s;
            edw[2000000 + p] = dinvs[250880 + s];
        } else if (gid < 2300000) {
            int i = gid - 2100000;
            int p = rowsts[264192 + p1[i]] + ranks[gid];
            elists[2100000 + p] = i;
        } else {
            int i = gid - 2300000;
            int p = rowsts[314368 + p2[i]] + ranks[gid];
            elists[2300000 + p] = i;
        }
    }
}

// ---------------- dedicated fused dual GEMM: U = prelu(X@W1+b1)@W2 -----------
__global__ __launch_bounds__(256) void k_gemm2(
    const float* __restrict__ X, const float* __restrict__ W1,
    const float* __restrict__ b1, const float* __restrict__ pa,
    const float* __restrict__ W2, float* __restrict__ OUT, int n)
{
    __shared__ float Xs[32][132];
    __shared__ float Wsh[32][132];
    int t = threadIdx.x;
    int cg = t & 31, rg = t >> 5;
    int base = blockIdx.x * 32;

    #pragma unroll
    for (int h = 0; h < 4; h++) {
        int fi = t + h * 256;
        int row = fi >> 5, q = fi & 31;
        float4 v = {0.f, 0.f, 0.f, 0.f};
        if (base + row < n) v = *(const float4*)(X + (size_t)(base + row) * 128 + q * 4);
        *(float4*)&Xs[row][q * 4] = v;
    }

    float acc[4][4];
    #pragma unroll
    for (int r = 0; r < 4; r++)
        #pragma unroll
        for (int c = 0; c < 4; c++) acc[r][c] = 0.f;

    for (int kc = 0; kc < 128; kc += 32) {
        __syncthreads();
        #pragma unroll
        for (int h = 0; h < 4; h++) {
            int fi = t + h * 256;
            int k = fi >> 5, q = fi & 31;
            *(float4*)&Wsh[k][q * 4] = *(const float4*)(W1 + (size_t)(kc + k) * 128 + q * 4);
        }
        __syncthreads();
        #pragma unroll
        for (int k4 = 0; k4 < 8; k4++) {
            int k = k4 * 4;
            float4 w0 = *(const float4*)&Wsh[k + 0][cg * 4];
            float4 w1 = *(const float4*)&Wsh[k + 1][cg * 4];
            float4 w2 = *(const float4*)&Wsh[k + 2][cg * 4];
            float4 w3 = *(const float4*)&Wsh[k + 3][cg * 4];
            #pragma unroll
            for (int r = 0; r < 4; r++) {
                float4 xv = *(const float4*)&Xs[rg * 4 + r][kc + k];
                acc[r][0] = fmaf(xv.w, w3.x, fmaf(xv.z, w2.x, fmaf(xv.y, w1.x, fmaf(xv.x, w0.x, acc[r][0]))));
                acc[r][1] = fmaf(xv.w, w3.y, fmaf(xv.z, w2.y, fmaf(xv.y, w1.y, fmaf(xv.x, w0.y, acc[r][1]))));
                acc[r][2] = fmaf(xv.w, w3.z, fmaf(xv.z, w2.z, fmaf(xv.y, w1.z, fmaf(xv.x, w0.z, acc[r][2]))));
                acc[r][3] = fmaf(xv.w, w3.w, fmaf(xv.z, w2.w, fmaf(xv.y, w1.w, fmaf(xv.x, w0.w, acc[r][3]))));
            }
        }
    }

    float4 bv = *(const float4*)(b1 + cg * 4);
    float4 pv = *(const float4*)(pa + cg * 4);
    __syncthreads();
    #pragma unroll
    for (int r = 0; r < 4; r++) {
        float v0 = acc[r][0] + bv.x; v0 = v0 > 0.f ? v0 : pv.x * v0;
        float v1 = acc[r][1] + bv.y; v1 = v1 > 0.f ? v1 : pv.y * v1;
        float v2 = acc[r][2] + bv.z; v2 = v2 > 0.f ? v2 : pv.z * v2;
        float v3 = acc[r][3] + bv.w; v3 = v3 > 0.f ? v3 : pv.w * v3;
        Xs[rg * 4 + r][cg * 4 + 0] = v0;
        Xs[rg * 4 + r][cg * 4 + 1] = v1;
        Xs[rg * 4 + r][cg * 4 + 2] = v2;
        Xs[rg * 4 + r][cg * 4 + 3] = v3;
        acc[r][0] = 0.f; acc[r][1] = 0.f; acc[r][2] = 0.f; acc[r][3] = 0.f;
    }

    for (int kc = 0; kc < 128; kc += 32) {
        __syncthreads();
        #pragma unroll
        for (int h = 0; h < 4; h++) {
            int fi = t + h * 256;
            int k = fi >> 5, q = fi & 31;
            *(float4*)&Wsh[k][q * 4] = *(const float4*)(W2 + (size_t)(kc + k) * 128 + q * 4);
        }
        __syncthreads();
        #pragma unroll
        for (int k4 = 0; k4 < 8; k4++) {
            int k = k4 * 4;
            float4 w0 = *(const float4*)&Wsh[k + 0][cg * 4];
            float4 w1 = *(const float4*)&Wsh[k + 1][cg * 4];
            float4 w2 = *(const float4*)&Wsh[k + 2][cg * 4];
            float4 w3 = *(const float4*)&Wsh[k + 3][cg * 4];
            #pragma unroll
            for (int r = 0; r < 4; r++) {
                float4 xv = *(const float4*)&Xs[rg * 4 + r][kc + k];
                acc[r][0] = fmaf(xv.w, w3.x, fmaf(xv.z, w2.x, fmaf(xv.y, w1.x, fmaf(xv.x, w0.x, acc[r][0]))));
                acc[r][1] = fmaf(xv.w, w3.y, fmaf(xv.z, w2.y, fmaf(xv.y, w1.y, fmaf(xv.x, w0.y, acc[r][1]))));
                acc[r][2] = fmaf(xv.w, w3.z, fmaf(xv.z, w2.z, fmaf(xv.y, w1.z, fmaf(xv.x, w0.z, acc[r][2]))));
                acc[r][3] = fmaf(xv.w, w3.w, fmaf(xv.z, w2.w, fmaf(xv.y, w1.w, fmaf(xv.x, w0.w, acc[r][3]))));
            }
        }
    }

    #pragma unroll
    for (int r = 0; r < 4; r++) {
        int row = base + rg * 4 + r;
        if (row >= n) break;
        float4 v;
        v.x = acc[r][0]; v.y = acc[r][1]; v.z = acc[r][2]; v.w = acc[r][3];
        *(float4*)(OUT + (size_t)row * 128 + cg * 4) = v;
    }
}

// ---------------- [n,128] @ [128,128] GEMM, 4x4 register tile ----------------
__global__ __launch_bounds__(256) void k_gemmT(
    const float* X, const float* __restrict__ W, float* OUT, int n)
{
    __shared__ float Xs[32][132];
    __shared__ float Ws[32][132];
    int t = threadIdx.x;
    int cg = t & 31, rg = t >> 5;
    int base = blockIdx.x * 32;

    #pragma unroll
    for (int h = 0; h < 4; h++) {
        int fi = t + h * 256;
        int row = fi >> 5, q = fi & 31;
        float4 v = {0.f, 0.f, 0.f, 0.f};
        if (base + row < n) v = *(const float4*)(X + (size_t)(base + row) * 128 + q * 4);
        *(float4*)&Xs[row][q * 4] = v;
    }

    float acc[4][4];
    #pragma unroll
    for (int r = 0; r < 4; r++)
        #pragma unroll
        for (int c = 0; c < 4; c++) acc[r][c] = 0.f;

    for (int kc = 0; kc < 128; kc += 32) {
        __syncthreads();
        #pragma unroll
        for (int h = 0; h < 4; h++) {
            int fi = t + h * 256;
            int k = fi >> 5, q = fi & 31;
            *(float4*)&Ws[k][q * 4] = *(const float4*)(W + (size_t)(kc + k) * 128 + q * 4);
        }
        __syncthreads();
        #pragma unroll
        for (int k4 = 0; k4 < 8; k4++) {
            int k = k4 * 4;
            float4 w0 = *(const float4*)&Ws[k + 0][cg * 4];
            float4 w1 = *(const float4*)&Ws[k + 1][cg * 4];
            float4 w2 = *(const float4*)&Ws[k + 2][cg * 4];
            float4 w3 = *(const float4*)&Ws[k + 3][cg * 4];
            #pragma unroll
            for (int r = 0; r < 4; r++) {
                float4 xv = *(const float4*)&Xs[rg * 4 + r][kc + k];
                acc[r][0] = fmaf(xv.w, w3.x, fmaf(xv.z, w2.x, fmaf(xv.y, w1.x, fmaf(xv.x, w0.x, acc[r][0]))));
                acc[r][1] = fmaf(xv.w, w3.y, fmaf(xv.z, w2.y, fmaf(xv.y, w1.y, fmaf(xv.x, w0.y, acc[r][1]))));
                acc[r][2] = fmaf(xv.w, w3.z, fmaf(xv.z, w2.z, fmaf(xv.y, w1.z, fmaf(xv.x, w0.z, acc[r][2]))));
                acc[r][3] = fmaf(xv.w, w3.w, fmaf(xv.z, w2.w, fmaf(xv.y, w1.w, fmaf(xv.x, w0.w, acc[r][3]))));
            }
        }
    }

    #pragma unroll
    for (int r = 0; r < 4; r++) {
        int row = base + rg * 4 + r;
        if (row >= n) break;
        float4 v;
        v.x = acc[r][0]; v.y = acc[r][1]; v.z = acc[r][2]; v.w = acc[r][3];
        *(float4*)(OUT + (size_t)row * 128 + cg * 4) = v;
    }
}

// ---------------- scan kernels ----------------------------------------------
__device__ __forceinline__ void seg_of_scanblk(int b, int& doff, int& bsoff, int& lb) {
    if (b < 196)      { doff = 0;      bsoff = 0;   lb = b; }
    else if (b < 245) { doff = 200704; bsoff = 196; lb = b - 196; }
    else if (b < 258) { doff = 250880; bsoff = 245; lb = b - 245; }
    else if (b < 307) { doff = 264192; bsoff = 258; lb = b - 258; }
    else              { doff = 314368; bsoff = 307; lb = b - 307; }
}

__global__ __launch_bounds__(256) void k_scan_all(
    const int* __restrict__ degs, int* __restrict__ rowsts, int* __restrict__ bsums)
{
    __shared__ int sh[256];
    int doff, bsoff, lb;
    seg_of_scanblk(blockIdx.x, doff, bsoff, lb);
    int t = threadIdx.x;
    int base = doff + lb * 1024 + t * 4;
    int v[4], s = 0;
    #pragma unroll
    for (int k = 0; k < 4; k++) { v[k] = degs[base + k]; s += v[k]; }
    sh[t] = s;
    __syncthreads();
    for (int off = 1; off < 256; off <<= 1) {
        int x = 0;
        if (t >= off) x = sh[t - off];
        __syncthreads();
        if (t >= off) sh[t] += x;
        __syncthreads();
    }
    int ex = sh[t] - s;
    if (t == 255) bsums[bsoff + lb] = sh[255];
    #pragma unroll
    for (int k = 0; k < 4; k++) { rowsts[base + k] = ex; ex += v[k]; }
}

__global__ __launch_bounds__(256) void k_scanadd_all(
    int* __restrict__ rowsts, const int* __restrict__ bsums,
    const int* __restrict__ degs, float* __restrict__ dinvs)
{
    __shared__ int sh[256];
    int doff, bsoff, lb;
    seg_of_scanblk(blockIdx.x, doff, bsoff, lb);
    int t = threadIdx.x;
    sh[t] = (t < lb) ? bsums[bsoff + t] : 0;
    __syncthreads();
    #pragma unroll
    for (int off = 128; off >= 1; off >>= 1) {
        if (t < off) sh[t] += sh[t + off];
        __syncthreads();
    }
    int add = sh[0];
    int base = doff + lb * 1024 + t * 4;
    bool dodinv = (doff <= 250880);
    #pragma unroll
    for (int k = 0; k < 4; k++) {
        int i = base + k;
        rowsts[i] += add;
        if (dodinv) dinvs[i] = rsqrtf((float)degs[i] + 1.0f);
    }
}

// ---------------- GCN gathers (permuted output for fused-seq pooling) --------
__global__ __launch_bounds__(256) void k_gatherU_perm(
    const float* __restrict__ U, const int* __restrict__ nl,
    const int* __restrict__ rowst, const int* __restrict__ elist,
    const float* __restrict__ edw, const float* __restrict__ dinv,
    const float* __restrict__ bias, const int* __restrict__ perm,
    float* __restrict__ out, int n)
{
    size_t gid = (size_t)blockIdx.x * 256 + threadIdx.x;
    int i = (int)(gid >> 5);
    if (i >= n) return;
    int l = (int)(gid & 31);
    int d = perm[i];
    const float4* Uv = (const float4*)U;
    float dd = dinv[d];
    float4 self = Uv[(size_t)nl[d] * 32 + l];
    float4 acc;
    acc.x = self.x * dd; acc.y = self.y * dd; acc.z = self.z * dd; acc.w = self.w * dd;
    int s0 = rowst[d], s1 = rowst[d + 1];
    for (int e = s0; e < s1; ++e) {
        int srow = elist[e];
        float w = edw[e];
        float4 v = Uv[(size_t)srow * 32 + l];
        acc.x = fmaf(v.x, w, acc.x);
        acc.y = fmaf(v.y, w, acc.y);
        acc.z = fmaf(v.z, w, acc.z);
        acc.w = fmaf(v.w, w, acc.w);
    }
    const float4 b = ((const float4*)bias)[l];
    float4 y;
    y.x = fmaxf(fmaf(acc.x, dd, b.x), 0.f);
    y.y = fmaxf(fmaf(acc.y, dd, b.y), 0.f);
    y.z = fmaxf(fmaf(acc.z, dd, b.z), 0.f);
    y.w = fmaxf(fmaf(acc.w, dd, b.w), 0.f);
    ((float4*)out)[(size_t)i * 32 + l] = y;
}

__global__ __launch_bounds__(256) void k_gather_perm(
    const float* __restrict__ h, const int* __restrict__ rowst,
    const int* __restrict__ elist, const float* __restrict__ edw,
    const float* __restrict__ dinv, const float* __restrict__ bias,
    const int* __restrict__ perm, float* __restrict__ out, int n)
{
    size_t gid = (size_t)blockIdx.x * 256 + threadIdx.x;
    int i = (int)(gid >> 5);
    if (i >= n) return;
    int l = (int)(gid & 31);
    int d = perm ? perm[i] : i;
    const float4* hv = (const float4*)h;
    float dd = dinv[d];
    float4 self = hv[(size_t)d * 32 + l];
    float4 acc;
    acc.x = self.x * dd; acc.y = self.y * dd; acc.z = self.z * dd; acc.w = self.w * dd;
    int s0 = rowst[d], s1 = rowst[d + 1];
    for (int e = s0; e < s1; ++e) {
        int srow = elist[e];
        float w = edw[e];
        float4 v = hv[(size_t)srow * 32 + l];
        acc.x = fmaf(v.x, w, acc.x);
        acc.y = fmaf(v.y, w, acc.y);
        acc.z = fmaf(v.z, w, acc.z);
        acc.w = fmaf(v.w, w, acc.w);
    }
    const float4 b = ((const float4*)bias)[l];
    float4 y;
    y.x = fmaxf(fmaf(acc.x, dd, b.x), 0.f);
    y.y = fmaxf(fmaf(acc.y, dd, b.y), 0.f);
    y.z = fmaxf(fmaf(acc.z, dd, b.z), 0.f);
    y.w = fmaxf(fmaf(acc.w, dd, b.w), 0.f);
    ((float4*)out)[(size_t)i * 32 + l] = y;
}

__global__ __launch_bounds__(256) void k_poolseq(
    const float* __restrict__ Yp, const int* __restrict__ prowst,
    float* __restrict__ out, int np)
{
    size_t gid = (size_t)blockIdx.x * 256 + threadIdx.x;
    int p = (int)(gid >> 5);
    if (p >= np) return;
    int l = (int)(gid & 31);
    const float4* yv = (const float4*)Yp;
    float4 acc = {0.f, 0.f, 0.f, 0.f};
    int c0 = prowst[p], c1 = prowst[p + 1];
    for (int c = c0; c < c1; ++c) {
        float4 v = yv[(size_t)c * 32 + l];
        acc.x += v.x; acc.y += v.y; acc.z += v.z; acc.w += v.w;
    }
    float4 y;
    y.x = fmaxf(acc.x, 0.f); y.y = fmaxf(acc.y, 0.f);
    y.z = fmaxf(acc.z, 0.f); y.w = fmaxf(acc.w, 0.f);
    ((float4*)out)[(size_t)p * 32 + l] = y;
}

__global__ __launch_bounds__(128) void k_bpool_all(
    const float* __restrict__ X1, const float* __restrict__ X2, const float* __restrict__ Y2,
    const int* __restrict__ b1, const int* __restrict__ b2, float* __restrict__ pl)
{
    int b = blockIdx.x;
    const float* src; const int* bidx; int coloff, n, r0;
    if (b < 391)      { src = X1; bidx = b1; coloff = 0;   n = 50000; r0 = b * 128; }
    else if (b < 489) { src = X2; bidx = b2; coloff = 128; n = 12500; r0 = (b - 391) * 128; }
    else              { src = Y2; bidx = b2; coloff = 256; n = 12500; r0 = (b - 489) * 128; }
    if (r0 >= n) return;
    int j = threadIdx.x;
    int r1 = min(r0 + 128, n);
    float acc = 0.f;
    int prev = bidx[r0];
    for (int r = r0; r < r1; ++r) {
        int bb = bidx[r];
        if (bb != prev) {
            unsafeAtomicAdd(&pl[(size_t)prev * 384 + coloff + j], acc);
            acc = 0.f; prev = bb;
        }
        acc += src[(size_t)r * 128 + j];
    }
    unsafeAtomicAdd(&pl[(size_t)prev * 384 + coloff + j], acc);
}

__global__ void k_mlp2(const float* __restrict__ PL,
                       const float* __restrict__ Wc1, const float* __restrict__ bc1,
                       const float* __restrict__ Wc2, const float* __restrict__ bc2,
                       float* __restrict__ out)
{
    __shared__ float as[384];
    __shared__ float zs[128];
    int r = blockIdx.x, j = threadIdx.x;
    as[j] = PL[(size_t)r * 384 + j];
    as[j + 128] = PL[(size_t)r * 384 + 128 + j];
    as[j + 256] = PL[(size_t)r * 384 + 256 + j];
    __syncthreads();
    float acc = bc1[j];
    for (int k = 0; k < 384; k++) acc = fmaf(as[k], Wc1[(size_t)k * 128 + j], acc);
    zs[j] = fmaxf(acc, 0.f);
    __syncthreads();
    float o = bc2[j];
    for (int k = 0; k < 128; k++) o = fmaf(zs[k], Wc2[(size_t)k * 128 + j], o);
    out[(size_t)r * 128 + j] = o;
}

extern "C" void kernel_launch(void* const* d_in, const int* in_sizes, int n_in,
                              void* d_out, int out_size, void* d_ws, size_t ws_size,
                              hipStream_t stream)
{
    const float* x_raw  = (const float*)d_in[0];
    const float* W_des  = (const float*)d_in[1];
    const float* b_des  = (const float*)d_in[2];
    const float* W_twe  = (const float*)d_in[3];
    const float* b_twe  = (const float*)d_in[4];
    const float* W_num  = (const float*)d_in[5];
    const float* b_num  = (const float*)d_in[6];
    const float* W_cat  = (const float*)d_in[7];
    const float* b_cat  = (const float*)d_in[8];
    const float* W_in   = (const float*)d_in[9];
    const float* b_in   = (const float*)d_in[10];
    const float* prelua = (const float*)d_in[11];
    const float* W_conv = (const float*)d_in[12];
    const float* b_conv = (const float*)d_in[13];
    const float* Wc1    = (const float*)d_in[14];
    const float* bc1    = (const float*)d_in[15];
    const float* Wc2    = (const float*)d_in[16];
    const float* bc2    = (const float*)d_in[17];
    const int* nodelist = (const int*)d_in[18];
    const int* e0       = (const int*)d_in[19];
    const int* e1       = (const int*)d_in[20];
    const int* e2       = (const int*)d_in[21];
    const int* parent1  = (const int*)d_in[22];
    const int* parent2  = (const int*)d_in[23];
    const int* batch1   = (const int*)d_in[24];
    const int* batch2   = (const int*)d_in[25];

    // ---- workspace layout (243 MB; CSR scratch does not alias ENC) ----
    float* WS  = (float*)d_ws;
    float* ENC = WS;                    // 50000*128
    float* U   = WS + 6400000;          // 50000*128
    float* H   = WS + 12800000;         // 50000*128
    float* Y   = WS + 19200000;         // 200000*128 (permuted L0 out; reused L1/L2)
    float* X1  = WS + 44800000;         // 50000*128
    float* X2  = WS + 51200000;         // 12500*128
    float* PL  = WS + 52800000;         // 128*384
    float* EDW = WS + 52900000;         // 2100000
    int*   DEGS   = (int*)(WS + 55000000);      // 327680
    int*   ROWSTS = DEGS + 327680;              // 327680
    float* DINVS  = (float*)(ROWSTS + 327680);  // 264192
    int*   BSUMS  = (int*)(DINVS + 264192);     // 512
    int*   RANKS  = BSUMS + 512;                // 2350000
    int*   ELISTS = RANKS + 2350000;            // 2350000

    hipMemsetAsync(PL, 0, (size_t)128 * 384 * 4, stream);
    hipMemsetAsync(DEGS, 0, (size_t)327680 * 4, stream);

    // ---- K1: encoder (reg-prefetch) || CSR count ----
    k_enc_count<<<ENC_BLOCKS + CNT_BLOCKS, 256, 0, stream>>>(
        x_raw, W_des, b_des, W_twe, b_twe, W_num, b_num, W_cat, b_cat, ENC,
        e0 + EE0, e1 + EE1, e2 + EE2, parent1, parent2, DEGS, RANKS);

    // ---- scans ----
    k_scan_all<<<320, 256, 0, stream>>>(DEGS, ROWSTS, BSUMS);
    k_scanadd_all<<<320, 256, 0, stream>>>(ROWSTS, BSUMS, DEGS, DINVS);

    // ---- scatter (dedicated, high occupancy) then dual GEMM ----
    k_scatter_all<<<CNT_BLOCKS, 256, 0, stream>>>(
        e0, e0 + EE0, e1, e1 + EE1, e2, e2 + EE2, parent1, parent2,
        nodelist, DINVS, ROWSTS, RANKS, ELISTS, EDW);
    k_gemm2<<<(N_USERS + 31) / 32, 256, 0, stream>>>(
        ENC, W_in, b_in, prelua, W_conv, U, N_USERS);

    // ---- layer 0: GCN in parent-child order -> Y (permuted); seq pool -> X1 --
    k_gatherU_perm<<<(int)(((size_t)NN0 * 32 + 255) / 256), 256, 0, stream>>>(
        U, nodelist, ROWSTS, ELISTS, EDW, DINVS, b_conv,
        ELISTS + 2100000, Y, NN0);
    k_poolseq<<<(int)(((size_t)NN1 * 32 + 255) / 256), 256, 0, stream>>>(
        Y, ROWSTS + 264192, X1, NN1);

    // ---- layer 1 ----
    k_gemmT<<<(NN1 + 31) / 32, 256, 0, stream>>>(X1, W_conv + 16384, H, NN1);
    k_gather_perm<<<(int)(((size_t)NN1 * 32 + 255) / 256), 256, 0, stream>>>(
        H, ROWSTS + 200704, ELISTS + 1600000, EDW + 1600000, DINVS + 200704,
        b_conv + 128, ELISTS + 2300000, Y, NN1);
    k_poolseq<<<(int)(((size_t)NN2 * 32 + 255) / 256), 256, 0, stream>>>(
        Y, ROWSTS + 314368, X2, NN2);

    // ---- layer 2 (plain order for bpool) ----
    k_gemmT<<<(NN2 + 31) / 32, 256, 0, stream>>>(X2, W_conv + 32768, H, NN2);
    k_gather_perm<<<(int)(((size_t)NN2 * 32 + 255) / 256), 256, 0, stream>>>(
        H, ROWSTS + 250880, ELISTS + 2000000, EDW + 2000000, DINVS + 250880,
        b_conv + 256, nullptr, Y, NN2);

    // ---- batch pooling (fused, sorted keys) ----
    k_bpool_all<<<587, 128, 0, stream>>>(X1, X2, Y, batch1, batch2, PL);

    // ---- final fused MLP ----
    k_mlp2<<<128, 128, 0, stream>>>(PL, Wc1, bc1, Wc2, bc2, (float*)d_out);
}

// Round 17
// 647.706 us; speedup vs baseline: 1.0166x; 1.0166x over previous
//
#include <hip/hip_runtime.h>

#define N_USERS 50000
#define NN0 200000
#define NN1 50000
#define NN2 12500
#define EE0 1600000
#define EE1 400000
#define EE2 100000

#define ENC_BLOCKS 782     // (50000+63)/64
#define CNT_BLOCKS 2295    // (587500+255)/256
#define GM2_BLOCKS 1563    // (50000+31)/32

// Padded segment geometry (1024 multiples):
// seg:      0:e0        1:e1      2:e2      3:parent1  4:parent2
// deg off:  0           200704    250880    264192     314368   (total 327680)
// scan blk: 196         49        13        49         13       (cum 196,245,258,307,320)
// bsum off: 0           196       245       258        307
// el off:   0           1600000   2000000   2100000    2300000

// ================= K1: encoder (blocks<782) + CSR count (rest) ===============
__global__ __launch_bounds__(256) void k_enc_count(
    const float* __restrict__ xr,
    const float* __restrict__ Wd, const float* __restrict__ bd,
    const float* __restrict__ Wt, const float* __restrict__ bt,
    const float* __restrict__ Wn, const float* __restrict__ bn,
    const float* __restrict__ Wc, const float* __restrict__ bc,
    float* __restrict__ h128,
    const int* __restrict__ d0, const int* __restrict__ d1, const int* __restrict__ d2,
    const int* __restrict__ p1, const int* __restrict__ p2,
    int* __restrict__ degs, int* __restrict__ ranks)
{
    __shared__ float XsB[4368];    // [0,2176): des [k][row]; [2192,4368): tweet
    __shared__ float Ws[32][68];
    __shared__ float xnc[64][8];
    __shared__ float Wl[8][64];

    if (blockIdx.x >= ENC_BLOCKS) {
        // ---------------- CSR count path ----------------
        int t0 = (blockIdx.x - ENC_BLOCKS) * 256 + threadIdx.x;
        if (t0 >= 587500) return;
        #pragma unroll
        for (int k = 0; k < 4; k++) {
            int gid = t0 + k * 587500;
            int idx;
            if (gid < 1600000)      idx = d0[gid];
            else if (gid < 2000000) idx = 200704 + d1[gid - 1600000];
            else if (gid < 2100000) idx = 250880 + d2[gid - 2000000];
            else if (gid < 2300000) idx = 264192 + p1[gid - 2100000];
            else                    idx = 314368 + p2[gid - 2300000];
            ranks[gid] = atomicAdd(&degs[idx], 1);
        }
        return;
    }

    // ---------------- encoder path ----------------
    int t = threadIdx.x;
    int lane = t & 63, wv = t >> 6;
    int cg = t & 15, rg = t >> 4;
    int base = blockIdx.x * 64;

    if (t < 64) {
        int row = base + t;
        if (row < N_USERS) {
            const float* xp = xr + (size_t)row * 1544;
            float4 a = *(const float4*)xp;
            float2 b2 = *(const float2*)(xp + 4);
            float2 c2 = *(const float2*)(xp + 774);
            xnc[t][0] = a.x; xnc[t][1] = a.y; xnc[t][2] = a.z; xnc[t][3] = a.w;
            xnc[t][4] = b2.x; xnc[t][5] = b2.y; xnc[t][6] = c2.x; xnc[t][7] = c2.y;
        } else {
            #pragma unroll
            for (int k = 0; k < 8; k++) xnc[t][k] = 0.f;
        }
    } else if (t >= 192) {
        int l = t - 192;
        #pragma unroll
        for (int k = 0; k < 8; k++) {
            float w = 0.f;
            if (l < 32) { if (k < 6) w = Wn[k * 32 + l]; }
            else        { if (k >= 6) w = Wc[(k - 6) * 32 + (l - 32)]; }
            Wl[k][l] = w;
        }
    }

    int srow = (lane & 15) + wv * 16;
    int grow = base + srow;
    bool vrow = grow < N_USERS;
    const float* xrow = xr + (size_t)grow * 1544;

    float acc[4][4];
    #pragma unroll
    for (int r = 0; r < 4; r++)
        #pragma unroll
        for (int c = 0; c < 4; c++) acc[r][c] = 0.f;

    for (int kc = 0; kc < 768; kc += 32) {
        __syncthreads();
        #pragma unroll
        for (int h = 0; h < 2; h++) {
            int q = (lane >> 4) + h * 4;
            float4 vd = {0.f, 0.f, 0.f, 0.f};
            float2 va = {0.f, 0.f}, vb = {0.f, 0.f};
            if (vrow) {
                const float* xp = xrow + kc + q * 4;
                vd = *(const float4*)(xp + 776);
                va = *(const float2*)(xp + 6);
                vb = *(const float2*)(xp + 8);
            }
            int k0 = q * 4;
            XsB[(k0 + 0) * 68 + srow] = vd.x;
            XsB[(k0 + 1) * 68 + srow] = vd.y;
            XsB[(k0 + 2) * 68 + srow] = vd.z;
            XsB[(k0 + 3) * 68 + srow] = vd.w;
            XsB[2192 + (k0 + 0) * 68 + srow] = va.x;
            XsB[2192 + (k0 + 1) * 68 + srow] = va.y;
            XsB[2192 + (k0 + 2) * 68 + srow] = vb.x;
            XsB[2192 + (k0 + 3) * 68 + srow] = vb.y;
        }
        #pragma unroll
        for (int h = 0; h < 2; h++) {
            int fi = t + h * 256;
            int k = fi >> 4, c4 = (fi & 15) * 4;
            float4 w = (c4 < 32) ? *(const float4*)(Wd + (size_t)(kc + k) * 32 + c4)
                                 : *(const float4*)(Wt + (size_t)(kc + k) * 32 + (c4 - 32));
            *(float4*)&Ws[k][c4] = w;
        }
        __syncthreads();

        const float* Xp = (cg < 8) ? XsB : (XsB + 2192);
        #pragma unroll 8
        for (int k = 0; k < 32; k++) {
            float4 xv = *(const float4*)(Xp + k * 68 + rg * 4);
            float4 wv2 = *(const float4*)&Ws[k][cg * 4];
            acc[0][0] = fmaf(xv.x, wv2.x, acc[0][0]);
            acc[0][1] = fmaf(xv.x, wv2.y, acc[0][1]);
            acc[0][2] = fmaf(xv.x, wv2.z, acc[0][2]);
            acc[0][3] = fmaf(xv.x, wv2.w, acc[0][3]);
            acc[1][0] = fmaf(xv.y, wv2.x, acc[1][0]);
            acc[1][1] = fmaf(xv.y, wv2.y, acc[1][1]);
            acc[1][2] = fmaf(xv.y, wv2.z, acc[1][2]);
            acc[1][3] = fmaf(xv.y, wv2.w, acc[1][3]);
            acc[2][0] = fmaf(xv.z, wv2.x, acc[2][0]);
            acc[2][1] = fmaf(xv.z, wv2.y, acc[2][1]);
            acc[2][2] = fmaf(xv.z, wv2.z, acc[2][2]);
            acc[2][3] = fmaf(xv.z, wv2.w, acc[2][3]);
            acc[3][0] = fmaf(xv.w, wv2.x, acc[3][0]);
            acc[3][1] = fmaf(xv.w, wv2.y, acc[3][1]);
            acc[3][2] = fmaf(xv.w, wv2.z, acc[3][2]);
            acc[3][3] = fmaf(xv.w, wv2.w, acc[3][3]);
        }
    }

    float bh[4], bl[4], wlv[8][4];
    #pragma unroll
    for (int c = 0; c < 4; c++) {
        int j = cg * 4 + c;
        bh[c] = (j < 32) ? bd[j] : bt[j - 32];
        bl[c] = (j < 32) ? bn[j] : bc[j - 32];
        #pragma unroll
        for (int k = 0; k < 8; k++) wlv[k][c] = Wl[k][j];
    }
    #pragma unroll
    for (int r = 0; r < 4; r++) {
        int lr = rg * 4 + r;
        int row = base + lr;
        if (row >= N_USERS) break;
        float4 hv;
        float* ph = &hv.x;
        #pragma unroll
        for (int c = 0; c < 4; c++) {
            float v = acc[r][c] + bh[c];
            ph[c] = v > 0.f ? v : 0.01f * v;
        }
        *(float4*)(h128 + (size_t)row * 128 + cg * 4) = hv;
        float4 lv;
        float* pl = &lv.x;
        #pragma unroll
        for (int c = 0; c < 4; c++) {
            float v = bl[c];
            #pragma unroll
            for (int k = 0; k < 8; k++) v = fmaf(xnc[lr][k], wlv[k][c], v);
            pl[c] = v > 0.f ? v : 0.01f * v;
        }
        *(float4*)(h128 + (size_t)row * 128 + 64 + cg * 4) = lv;
    }
}

// ======== K2: fused dual GEMM (blocks<1563) + atomic-free scatter (rest) =====
__global__ __launch_bounds__(256) void k_gemm2_scatter(
    const float* __restrict__ X, const float* __restrict__ W1,
    const float* __restrict__ b1, const float* __restrict__ pa,
    const float* __restrict__ W2, float* __restrict__ OUT, int n,
    const int* __restrict__ s0, const int* __restrict__ d0,
    const int* __restrict__ s1, const int* __restrict__ d1,
    const int* __restrict__ s2, const int* __restrict__ d2,
    const int* __restrict__ p1, const int* __restrict__ p2,
    const int* __restrict__ nl, const float* __restrict__ dinvs,
    const int* __restrict__ rowsts, const int* __restrict__ ranks,
    int* __restrict__ elists, float* __restrict__ edw)
{
    __shared__ float Xs[32][132];
    __shared__ float Wsh[32][132];

    if (blockIdx.x >= GM2_BLOCKS) {
        // ---------------- scatter path ----------------
        int t0 = (blockIdx.x - GM2_BLOCKS) * 256 + threadIdx.x;
        if (t0 >= 587500) return;
        #pragma unroll
        for (int k = 0; k < 4; k++) {
            int gid = t0 + k * 587500;
            if (gid < 1600000) {
                int s = s0[gid];
                int p = rowsts[d0[gid]] + ranks[gid];
                elists[p] = nl[s];
                edw[p] = dinvs[s];
            } else if (gid < 2000000) {
                int i = gid - 1600000;
                int s = s1[i];
                int p = rowsts[200704 + d1[i]] + ranks[gid];
                elists[1600000 + p] = s;
                edw[1600000 + p] = dinvs[200704 + s];
            } else if (gid < 2100000) {
                int i = gid - 2000000;
                int s = s2[i];
                int p = rowsts[250880 + d2[i]] + ranks[gid];
                elists[2000000 + p] = s;
                edw[2000000 + p] = dinvs[250880 + s];
            } else if (gid < 2300000) {
                int i = gid - 2100000;
                int p = rowsts[264192 + p1[i]] + ranks[gid];
                elists[2100000 + p] = i;
            } else {
                int i = gid - 2300000;
                int p = rowsts[314368 + p2[i]] + ranks[gid];
                elists[2300000 + p] = i;
            }
        }
        return;
    }

    // ---------------- gemm2 path ----------------
    int t = threadIdx.x;
    int cg = t & 31, rg = t >> 5;
    int base = blockIdx.x * 32;

    #pragma unroll
    for (int h = 0; h < 4; h++) {
        int fi = t + h * 256;
        int row = fi >> 5, q = fi & 31;
        float4 v = {0.f, 0.f, 0.f, 0.f};
        if (base + row < n) v = *(const float4*)(X + (size_t)(base + row) * 128 + q * 4);
        *(float4*)&Xs[row][q * 4] = v;
    }

    float acc[4][4];
    #pragma unroll
    for (int r = 0; r < 4; r++)
        #pragma unroll
        for (int c = 0; c < 4; c++) acc[r][c] = 0.f;

    for (int kc = 0; kc < 128; kc += 32) {
        __syncthreads();
        #pragma unroll
        for (int h = 0; h < 4; h++) {
            int fi = t + h * 256;
            int k = fi >> 5, q = fi & 31;
            *(float4*)&Wsh[k][q * 4] = *(const float4*)(W1 + (size_t)(kc + k) * 128 + q * 4);
        }
        __syncthreads();
        #pragma unroll
        for (int k4 = 0; k4 < 8; k4++) {
            int k = k4 * 4;
            float4 w0 = *(const float4*)&Wsh[k + 0][cg * 4];
            float4 w1 = *(const float4*)&Wsh[k + 1][cg * 4];
            float4 w2 = *(const float4*)&Wsh[k + 2][cg * 4];
            float4 w3 = *(const float4*)&Wsh[k + 3][cg * 4];
            #pragma unroll
            for (int r = 0; r < 4; r++) {
                float4 xv = *(const float4*)&Xs[rg * 4 + r][kc + k];
                acc[r][0] = fmaf(xv.w, w3.x, fmaf(xv.z, w2.x, fmaf(xv.y, w1.x, fmaf(xv.x, w0.x, acc[r][0]))));
                acc[r][1] = fmaf(xv.w, w3.y, fmaf(xv.z, w2.y, fmaf(xv.y, w1.y, fmaf(xv.x, w0.y, acc[r][1]))));
                acc[r][2] = fmaf(xv.w, w3.z, fmaf(xv.z, w2.z, fmaf(xv.y, w1.z, fmaf(xv.x, w0.z, acc[r][2]))));
                acc[r][3] = fmaf(xv.w, w3.w, fmaf(xv.z, w2.w, fmaf(xv.y, w1.w, fmaf(xv.x, w0.w, acc[r][3]))));
            }
        }
    }

    float4 bv = *(const float4*)(b1 + cg * 4);
    float4 pv = *(const float4*)(pa + cg * 4);
    __syncthreads();
    #pragma unroll
    for (int r = 0; r < 4; r++) {
        float v0 = acc[r][0] + bv.x; v0 = v0 > 0.f ? v0 : pv.x * v0;
        float v1 = acc[r][1] + bv.y; v1 = v1 > 0.f ? v1 : pv.y * v1;
        float v2 = acc[r][2] + bv.z; v2 = v2 > 0.f ? v2 : pv.z * v2;
        float v3 = acc[r][3] + bv.w; v3 = v3 > 0.f ? v3 : pv.w * v3;
        Xs[rg * 4 + r][cg * 4 + 0] = v0;
        Xs[rg * 4 + r][cg * 4 + 1] = v1;
        Xs[rg * 4 + r][cg * 4 + 2] = v2;
        Xs[rg * 4 + r][cg * 4 + 3] = v3;
        acc[r][0] = 0.f; acc[r][1] = 0.f; acc[r][2] = 0.f; acc[r][3] = 0.f;
    }

    for (int kc = 0; kc < 128; kc += 32) {
        __syncthreads();
        #pragma unroll
        for (int h = 0; h < 4; h++) {
            int fi = t + h * 256;
            int k = fi >> 5, q = fi & 31;
            *(float4*)&Wsh[k][q * 4] = *(const float4*)(W2 + (size_t)(kc + k) * 128 + q * 4);
        }
        __syncthreads();
        #pragma unroll
        for (int k4 = 0; k4 < 8; k4++) {
            int k = k4 * 4;
            float4 w0 = *(const float4*)&Wsh[k + 0][cg * 4];
            float4 w1 = *(const float4*)&Wsh[k + 1][cg * 4];
            float4 w2 = *(const float4*)&Wsh[k + 2][cg * 4];
            float4 w3 = *(const float4*)&Wsh[k + 3][cg * 4];
            #pragma unroll
            for (int r = 0; r < 4; r++) {
                float4 xv = *(const float4*)&Xs[rg * 4 + r][kc + k];
                acc[r][0] = fmaf(xv.w, w3.x, fmaf(xv.z, w2.x, fmaf(xv.y, w1.x, fmaf(xv.x, w0.x, acc[r][0]))));
                acc[r][1] = fmaf(xv.w, w3.y, fmaf(xv.z, w2.y, fmaf(xv.y, w1.y, fmaf(xv.x, w0.y, acc[r][1]))));
                acc[r][2] = fmaf(xv.w, w3.z, fmaf(xv.z, w2.z, fmaf(xv.y, w1.z, fmaf(xv.x, w0.z, acc[r][2]))));
                acc[r][3] = fmaf(xv.w, w3.w, fmaf(xv.z, w2.w, fmaf(xv.y, w1.w, fmaf(xv.x, w0.w, acc[r][3]))));
            }
        }
    }

    #pragma unroll
    for (int r = 0; r < 4; r++) {
        int row = base + rg * 4 + r;
        if (row >= n) break;
        float4 v;
        v.x = acc[r][0]; v.y = acc[r][1]; v.z = acc[r][2]; v.w = acc[r][3];
        *(float4*)(OUT + (size_t)row * 128 + cg * 4) = v;
    }
}

// ---------------- [n,128] @ [128,128] GEMM, 4x4 register tile ----------------
__global__ __launch_bounds__(256) void k_gemmT(
    const float* X, const float* __restrict__ W, float* OUT, int n)
{
    __shared__ float Xs[32][132];
    __shared__ float Ws[32][132];
    int t = threadIdx.x;
    int cg = t & 31, rg = t >> 5;
    int base = blockIdx.x * 32;

    #pragma unroll
    for (int h = 0; h < 4; h++) {
        int fi = t + h * 256;
        int row = fi >> 5, q = fi & 31;
        float4 v = {0.f, 0.f, 0.f, 0.f};
        if (base + row < n) v = *(const float4*)(X + (size_t)(base + row) * 128 + q * 4);
        *(float4*)&Xs[row][q * 4] = v;
    }

    float acc[4][4];
    #pragma unroll
    for (int r = 0; r < 4; r++)
        #pragma unroll
        for (int c = 0; c < 4; c++) acc[r][c] = 0.f;

    for (int kc = 0; kc < 128; kc += 32) {
        __syncthreads();
        #pragma unroll
        for (int h = 0; h < 4; h++) {
            int fi = t + h * 256;
            int k = fi >> 5, q = fi & 31;
            *(float4*)&Ws[k][q * 4] = *(const float4*)(W + (size_t)(kc + k) * 128 + q * 4);
        }
        __syncthreads();
        #pragma unroll
        for (int k4 = 0; k4 < 8; k4++) {
            int k = k4 * 4;
            float4 w0 = *(const float4*)&Ws[k + 0][cg * 4];
            float4 w1 = *(const float4*)&Ws[k + 1][cg * 4];
            float4 w2 = *(const float4*)&Ws[k + 2][cg * 4];
            float4 w3 = *(const float4*)&Ws[k + 3][cg * 4];
            #pragma unroll
            for (int r = 0; r < 4; r++) {
                float4 xv = *(const float4*)&Xs[rg * 4 + r][kc + k];
                acc[r][0] = fmaf(xv.w, w3.x, fmaf(xv.z, w2.x, fmaf(xv.y, w1.x, fmaf(xv.x, w0.x, acc[r][0]))));
                acc[r][1] = fmaf(xv.w, w3.y, fmaf(xv.z, w2.y, fmaf(xv.y, w1.y, fmaf(xv.x, w0.y, acc[r][1]))));
                acc[r][2] = fmaf(xv.w, w3.z, fmaf(xv.z, w2.z, fmaf(xv.y, w1.z, fmaf(xv.x, w0.z, acc[r][2]))));
                acc[r][3] = fmaf(xv.w, w3.w, fmaf(xv.z, w2.w, fmaf(xv.y, w1.w, fmaf(xv.x, w0.w, acc[r][3]))));
            }
        }
    }

    #pragma unroll
    for (int r = 0; r < 4; r++) {
        int row = base + rg * 4 + r;
        if (row >= n) break;
        float4 v;
        v.x = acc[r][0]; v.y = acc[r][1]; v.z = acc[r][2]; v.w = acc[r][3];
        *(float4*)(OUT + (size_t)row * 128 + cg * 4) = v;
    }
}

// ---------------- scan kernels ----------------------------------------------
__device__ __forceinline__ void seg_of_scanblk(int b, int& doff, int& bsoff, int& lb) {
    if (b < 196)      { doff = 0;      bsoff = 0;   lb = b; }
    else if (b < 245) { doff = 200704; bsoff = 196; lb = b - 196; }
    else if (b < 258) { doff = 250880; bsoff = 245; lb = b - 245; }
    else if (b < 307) { doff = 264192; bsoff = 258; lb = b - 258; }
    else              { doff = 314368; bsoff = 307; lb = b - 307; }
}

__global__ __launch_bounds__(256) void k_scan_all(
    const int* __restrict__ degs, int* __restrict__ rowsts, int* __restrict__ bsums)
{
    __shared__ int sh[256];
    int doff, bsoff, lb;
    seg_of_scanblk(blockIdx.x, doff, bsoff, lb);
    int t = threadIdx.x;
    int base = doff + lb * 1024 + t * 4;
    int v[4], s = 0;
    #pragma unroll
    for (int k = 0; k < 4; k++) { v[k] = degs[base + k]; s += v[k]; }
    sh[t] = s;
    __syncthreads();
    for (int off = 1; off < 256; off <<= 1) {
        int x = 0;
        if (t >= off) x = sh[t - off];
        __syncthreads();
        if (t >= off) sh[t] += x;
        __syncthreads();
    }
    int ex = sh[t] - s;
    if (t == 255) bsums[bsoff + lb] = sh[255];
    #pragma unroll
    for (int k = 0; k < 4; k++) { rowsts[base + k] = ex; ex += v[k]; }
}

__global__ __launch_bounds__(256) void k_scanadd_all(
    int* __restrict__ rowsts, const int* __restrict__ bsums,
    const int* __restrict__ degs, float* __restrict__ dinvs)
{
    __shared__ int sh[256];
    int doff, bsoff, lb;
    seg_of_scanblk(blockIdx.x, doff, bsoff, lb);
    int t = threadIdx.x;
    sh[t] = (t < lb) ? bsums[bsoff + t] : 0;
    __syncthreads();
    #pragma unroll
    for (int off = 128; off >= 1; off >>= 1) {
        if (t < off) sh[t] += sh[t + off];
        __syncthreads();
    }
    int add = sh[0];
    int base = doff + lb * 1024 + t * 4;
    bool dodinv = (doff <= 250880);
    #pragma unroll
    for (int k = 0; k < 4; k++) {
        int i = base + k;
        rowsts[i] += add;
        if (dodinv) dinvs[i] = rsqrtf((float)degs[i] + 1.0f);
    }
}

// ---------------- GCN gathers (permuted output for fused-seq pooling) --------
__global__ __launch_bounds__(256) void k_gatherU_perm(
    const float* __restrict__ U, const int* __restrict__ nl,
    const int* __restrict__ rowst, const int* __restrict__ elist,
    const float* __restrict__ edw, const float* __restrict__ dinv,
    const float* __restrict__ bias, const int* __restrict__ perm,
    float* __restrict__ out, int n)
{
    size_t gid = (size_t)blockIdx.x * 256 + threadIdx.x;
    int i = (int)(gid >> 5);
    if (i >= n) return;
    int l = (int)(gid & 31);
    int d = perm[i];
    const float4* Uv = (const float4*)U;
    float dd = dinv[d];
    float4 self = Uv[(size_t)nl[d] * 32 + l];
    float4 acc;
    acc.x = self.x * dd; acc.y = self.y * dd; acc.z = self.z * dd; acc.w = self.w * dd;
    int s0 = rowst[d], s1 = rowst[d + 1];
    for (int e = s0; e < s1; ++e) {
        int srow = elist[e];
        float w = edw[e];
        float4 v = Uv[(size_t)srow * 32 + l];
        acc.x = fmaf(v.x, w, acc.x);
        acc.y = fmaf(v.y, w, acc.y);
        acc.z = fmaf(v.z, w, acc.z);
        acc.w = fmaf(v.w, w, acc.w);
    }
    const float4 b = ((const float4*)bias)[l];
    float4 y;
    y.x = fmaxf(fmaf(acc.x, dd, b.x), 0.f);
    y.y = fmaxf(fmaf(acc.y, dd, b.y), 0.f);
    y.z = fmaxf(fmaf(acc.z, dd, b.z), 0.f);
    y.w = fmaxf(fmaf(acc.w, dd, b.w), 0.f);
    ((float4*)out)[(size_t)i * 32 + l] = y;
}

__global__ __launch_bounds__(256) void k_gather_perm(
    const float* __restrict__ h, const int* __restrict__ rowst,
    const int* __restrict__ elist, const float* __restrict__ edw,
    const float* __restrict__ dinv, const float* __restrict__ bias,
    const int* __restrict__ perm, float* __restrict__ out, int n)
{
    size_t gid = (size_t)blockIdx.x * 256 + threadIdx.x;
    int i = (int)(gid >> 5);
    if (i >= n) return;
    int l = (int)(gid & 31);
    int d = perm ? perm[i] : i;
    const float4* hv = (const float4*)h;
    float dd = dinv[d];
    float4 self = hv[(size_t)d * 32 + l];
    float4 acc;
    acc.x = self.x * dd; acc.y = self.y * dd; acc.z = self.z * dd; acc.w = self.w * dd;
    int s0 = rowst[d], s1 = rowst[d + 1];
    for (int e = s0; e < s1; ++e) {
        int srow = elist[e];
        float w = edw[e];
        float4 v = hv[(size_t)srow * 32 + l];
        acc.x = fmaf(v.x, w, acc.x);
        acc.y = fmaf(v.y, w, acc.y);
        acc.z = fmaf(v.z, w, acc.z);
        acc.w = fmaf(v.w, w, acc.w);
    }
    const float4 b = ((const float4*)bias)[l];
    float4 y;
    y.x = fmaxf(fmaf(acc.x, dd, b.x), 0.f);
    y.y = fmaxf(fmaf(acc.y, dd, b.y), 0.f);
    y.z = fmaxf(fmaf(acc.z, dd, b.z), 0.f);
    y.w = fmaxf(fmaf(acc.w, dd, b.w), 0.f);
    ((float4*)out)[(size_t)i * 32 + l] = y;
}

// sequential-range pool: out[p] = relu(sum Yp[prowst[p]..prowst[p+1]))
__global__ __launch_bounds__(256) void k_poolseq(
    const float* __restrict__ Yp, const int* __restrict__ prowst,
    float* __restrict__ out, int np)
{
    size_t gid = (size_t)blockIdx.x * 256 + threadIdx.x;
    int p = (int)(gid >> 5);
    if (p >= np) return;
    int l = (int)(gid & 31);
    const float4* yv = (const float4*)Yp;
    float4 acc = {0.f, 0.f, 0.f, 0.f};
    int c0 = prowst[p], c1 = prowst[p + 1];
    for (int c = c0; c < c1; ++c) {
        float4 v = yv[(size_t)c * 32 + l];
        acc.x += v.x; acc.y += v.y; acc.z += v.z; acc.w += v.w;
    }
    float4 y;
    y.x = fmaxf(acc.x, 0.f); y.y = fmaxf(acc.y, 0.f);
    y.z = fmaxf(acc.z, 0.f); y.w = fmaxf(acc.w, 0.f);
    ((float4*)out)[(size_t)p * 32 + l] = y;
}

__global__ __launch_bounds__(128) void k_bpool_all(
    const float* __restrict__ X1, const float* __restrict__ X2, const float* __restrict__ Y2,
    const int* __restrict__ b1, const int* __restrict__ b2, float* __restrict__ pl)
{
    int b = blockIdx.x;
    const float* src; const int* bidx; int coloff, n, r0;
    if (b < 391)      { src = X1; bidx = b1; coloff = 0;   n = 50000; r0 = b * 128; }
    else if (b < 489) { src = X2; bidx = b2; coloff = 128; n = 12500; r0 = (b - 391) * 128; }
    else              { src = Y2; bidx = b2; coloff = 256; n = 12500; r0 = (b - 489) * 128; }
    if (r0 >= n) return;
    int j = threadIdx.x;
    int r1 = min(r0 + 128, n);
    float acc = 0.f;
    int prev = bidx[r0];
    for (int r = r0; r < r1; ++r) {
        int bb = bidx[r];
        if (bb != prev) {
            unsafeAtomicAdd(&pl[(size_t)prev * 384 + coloff + j], acc);
            acc = 0.f; prev = bb;
        }
        acc += src[(size_t)r * 128 + j];
    }
    unsafeAtomicAdd(&pl[(size_t)prev * 384 + coloff + j], acc);
}

__global__ void k_mlp2(const float* __restrict__ PL,
                       const float* __restrict__ Wc1, const float* __restrict__ bc1,
                       const float* __restrict__ Wc2, const float* __restrict__ bc2,
                       float* __restrict__ out)
{
    __shared__ float as[384];
    __shared__ float zs[128];
    int r = blockIdx.x, j = threadIdx.x;
    as[j] = PL[(size_t)r * 384 + j];
    as[j + 128] = PL[(size_t)r * 384 + 128 + j];
    as[j + 256] = PL[(size_t)r * 384 + 256 + j];
    __syncthreads();
    float acc = bc1[j];
    for (int k = 0; k < 384; k++) acc = fmaf(as[k], Wc1[(size_t)k * 128 + j], acc);
    zs[j] = fmaxf(acc, 0.f);
    __syncthreads();
    float o = bc2[j];
    for (int k = 0; k < 128; k++) o = fmaf(zs[k], Wc2[(size_t)k * 128 + j], o);
    out[(size_t)r * 128 + j] = o;
}

extern "C" void kernel_launch(void* const* d_in, const int* in_sizes, int n_in,
                              void* d_out, int out_size, void* d_ws, size_t ws_size,
                              hipStream_t stream)
{
    const float* x_raw  = (const float*)d_in[0];
    const float* W_des  = (const float*)d_in[1];
    const float* b_des  = (const float*)d_in[2];
    const float* W_twe  = (const float*)d_in[3];
    const float* b_twe  = (const float*)d_in[4];
    const float* W_num  = (const float*)d_in[5];
    const float* b_num  = (const float*)d_in[6];
    const float* W_cat  = (const float*)d_in[7];
    const float* b_cat  = (const float*)d_in[8];
    const float* W_in   = (const float*)d_in[9];
    const float* b_in   = (const float*)d_in[10];
    const float* prelua = (const float*)d_in[11];
    const float* W_conv = (const float*)d_in[12];
    const float* b_conv = (const float*)d_in[13];
    const float* Wc1    = (const float*)d_in[14];
    const float* bc1    = (const float*)d_in[15];
    const float* Wc2    = (const float*)d_in[16];
    const float* bc2    = (const float*)d_in[17];
    const int* nodelist = (const int*)d_in[18];
    const int* e0       = (const int*)d_in[19];
    const int* e1       = (const int*)d_in[20];
    const int* e2       = (const int*)d_in[21];
    const int* parent1  = (const int*)d_in[22];
    const int* parent2  = (const int*)d_in[23];
    const int* batch1   = (const int*)d_in[24];
    const int* batch2   = (const int*)d_in[25];

    // ---- workspace layout (243 MB; CSR scratch does not alias ENC) ----
    float* WS  = (float*)d_ws;
    float* ENC = WS;                    // 50000*128
    float* U   = WS + 6400000;          // 50000*128
    float* H   = WS + 12800000;         // 50000*128
    float* Y   = WS + 19200000;         // 200000*128 (permuted L0 out; reused L1/L2)
    float* X1  = WS + 44800000;         // 50000*128
    float* X2  = WS + 51200000;         // 12500*128
    float* PL  = WS + 52800000;         // 128*384
    float* EDW = WS + 52900000;         // 2100000
    int*   DEGS   = (int*)(WS + 55000000);      // 327680
    int*   ROWSTS = DEGS + 327680;              // 327680
    float* DINVS  = (float*)(ROWSTS + 327680);  // 264192
    int*   BSUMS  = (int*)(DINVS + 264192);     // 512
    int*   RANKS  = BSUMS + 512;                // 2350000
    int*   ELISTS = RANKS + 2350000;            // 2350000

    hipMemsetAsync(PL, 0, (size_t)128 * 384 * 4, stream);
    hipMemsetAsync(DEGS, 0, (size_t)327680 * 4, stream);

    // ---- K1: encoder || CSR count (independent work, one launch) ----
    k_enc_count<<<ENC_BLOCKS + CNT_BLOCKS, 256, 0, stream>>>(
        x_raw, W_des, b_des, W_twe, b_twe, W_num, b_num, W_cat, b_cat, ENC,
        e0 + EE0, e1 + EE1, e2 + EE2, parent1, parent2, DEGS, RANKS);

    // ---- scans ----
    k_scan_all<<<320, 256, 0, stream>>>(DEGS, ROWSTS, BSUMS);
    k_scanadd_all<<<320, 256, 0, stream>>>(ROWSTS, BSUMS, DEGS, DINVS);

    // ---- K2: dual GEMM (U) || atomic-free scatter ----
    k_gemm2_scatter<<<GM2_BLOCKS + CNT_BLOCKS, 256, 0, stream>>>(
        ENC, W_in, b_in, prelua, W_conv, U, N_USERS,
        e0, e0 + EE0, e1, e1 + EE1, e2, e2 + EE2, parent1, parent2,
        nodelist, DINVS, ROWSTS, RANKS, ELISTS, EDW);

    // ---- layer 0: GCN in parent-child order -> Y (permuted); seq pool -> X1 --
    k_gatherU_perm<<<(int)(((size_t)NN0 * 32 + 255) / 256), 256, 0, stream>>>(
        U, nodelist, ROWSTS, ELISTS, EDW, DINVS, b_conv,
        ELISTS + 2100000, Y, NN0);
    k_poolseq<<<(int)(((size_t)NN1 * 32 + 255) / 256), 256, 0, stream>>>(
        Y, ROWSTS + 264192, X1, NN1);

    // ---- layer 1 ----
    k_gemmT<<<(NN1 + 31) / 32, 256, 0, stream>>>(X1, W_conv + 16384, H, NN1);
    k_gather_perm<<<(int)(((size_t)NN1 * 32 + 255) / 256), 256, 0, stream>>>(
        H, ROWSTS + 200704, ELISTS + 1600000, EDW + 1600000, DINVS + 200704,
        b_conv + 128, ELISTS + 2300000, Y, NN1);
    k_poolseq<<<(int)(((size_t)NN2 * 32 + 255) / 256), 256, 0, stream>>>(
        Y, ROWSTS + 314368, X2, NN2);

    // ---- layer 2 (plain order for bpool) ----
    k_gemmT<<<(NN2 + 31) / 32, 256, 0, stream>>>(X2, W_conv + 32768, H, NN2);
    k_gather_perm<<<(int)(((size_t)NN2 * 32 + 255) / 256), 256, 0, stream>>>(
        H, ROWSTS + 250880, ELISTS + 2000000, EDW + 2000000, DINVS + 250880,
        b_conv + 256, nullptr, Y, NN2);

    // ---- batch pooling (fused, sorted keys) ----
    k_bpool_all<<<587, 128, 0, stream>>>(X1, X2, Y, batch1, batch2, PL);

    // ---- final fused MLP ----
    k_mlp2<<<128, 128, 0, stream>>>(PL, Wc1, bc1, Wc2, bc2, (float*)d_out);
}